// Round 5
// baseline (1157.500 us; speedup 1.0000x reference)
//
#include <hip/hip_runtime.h>
#include <math.h>

#define H 1024
#define H2 2048
#define MTOK 65536          // B*S*L = 4*2048*8
#define TM 128
#define TN 64
#define BK 64

typedef __attribute__((ext_vector_type(8))) short short8;
typedef __attribute__((ext_vector_type(4))) float f32x4;

// ---------------- ws layout (bytes) ----------------
#define WS_R_OFF    0                         // 64 floats
#define WS_BS_OFF   256                       // 8 floats
#define WS_B2_OFF   4096                      // 1024 floats (br @ Wg2^T)
#define WS_WR_OFF   16384                     // bf16 1024*1024   (2 MB)
#define WS_WG_OFF   (16384 + 2*1024*1024)     // bf16 1024*2048   (4 MB)
#define WS_WRT_OFF  (WS_WG_OFF + 4*1024*1024) // bf16 Wr^T 1024*1024 (2 MB)
#define WS_WC_OFF   (WS_WRT_OFF + 2*1024*1024)// bf16 Wc 1024*1024 (2 MB)
#define WS_XB_OFF   (16ull*1024*1024)         // bf16 MTOK*1024 (128 MB)
#define WS_NEED     (WS_XB_OFF + (size_t)MTOK*H*2)

static __device__ __forceinline__ unsigned short f2bf(float f) {
    unsigned int u = __float_as_uint(f);
    u = u + 0x7fffu + ((u >> 16) & 1u);       // RNE
    return (unsigned short)(u >> 16);
}
static __device__ __forceinline__ float bf2f(unsigned short s) {
    return __uint_as_float(((unsigned int)s) << 16);
}
static __device__ __forceinline__ void gload16(const void* g, void* l) {
    __builtin_amdgcn_global_load_lds(
        (const __attribute__((address_space(1))) void*)g,
        (__attribute__((address_space(3))) void*)l, 16, 0, 0);
}

// ---------------- routing matrix ----------------
__global__ void k_routing(const float* __restrict__ lp, const float* __restrict__ thr,
                          float* __restrict__ wsR, float* __restrict__ wsBS) {
    int t = threadIdx.x;            // 0..63
    int i = t >> 3, j = t & 7;
    float mx = 0.5f * (lp[i*3+0] + lp[j*3+0]);
    float my = 0.5f * (lp[i*3+1] + lp[j*3+1]);
    float mz = 0.5f * (lp[i*3+2] + lp[j*3+2]);
    float f = sinf(mx)*cosf(my) + sinf(my)*cosf(mz) + sinf(mz)*cosf(mx) - thr[0];
    float r = 1.0f / (1.0f + expf(-2.0f * f));
    if (i == j) r = 1.0f;
    float s = r;
    s += __shfl_xor(s, 1, 64);
    s += __shfl_xor(s, 2, 64);
    s += __shfl_xor(s, 4, 64);
    float R = r / (s + 1e-6f);
    wsR[t] = R;
    if (j == 0) wsBS[i] = s / (s + 1e-6f);
}

// ---------------- fp32 -> bf16 convert ----------------
__global__ void k_f32_to_bf16(const float* __restrict__ src, unsigned short* __restrict__ dst, int n4) {
    int i = blockIdx.x * blockDim.x + threadIdx.x;
    int stride = gridDim.x * blockDim.x;
    for (; i < n4; i += stride) {
        float4 v = reinterpret_cast<const float4*>(src)[i];
        ushort4 o = make_ushort4(f2bf(v.x), f2bf(v.y), f2bf(v.z), f2bf(v.w));
        reinterpret_cast<ushort4*>(dst)[i] = o;
    }
}

// ---------------- Wr^T (fp32 [d][k] -> bf16 [k][d]) ----------------
__global__ __launch_bounds__(256) void k_transp(const float* __restrict__ src,
                                                unsigned short* __restrict__ dst) {
    __shared__ unsigned short t[64][65];
    const int bx = blockIdx.x & 15;   // k-tile
    const int by = blockIdx.x >> 4;   // d-tile
    const int tid = threadIdx.x;
#pragma unroll
    for (int q = 0; q < 16; ++q) {
        int s = q * 256 + tid;
        int r = s >> 6, c = s & 63;
        t[r][c] = f2bf(src[(size_t)(by*64 + r) * H + bx*64 + c]);
    }
    __syncthreads();
#pragma unroll
    for (int q = 0; q < 16; ++q) {
        int s = q * 256 + tid;
        int r = s >> 6, c = s & 63;
        dst[(size_t)(bx*64 + r) * H + by*64 + c] = t[c][r];
    }
}

// ---------------- b2[e] = sum_d br[d] * Wg[e][H+d]  (fp32, exact) ----------------
__global__ void k_brw2(const float* __restrict__ br, const float* __restrict__ Wg,
                       float* __restrict__ b2) {
    const int e = blockIdx.x;
    const int lane = threadIdx.x;    // 64
    float s = 0.0f;
    for (int d = lane; d < H; d += 64)
        s += br[d] * Wg[(size_t)e * H2 + H + d];
    s += __shfl_xor(s, 1, 64);
    s += __shfl_xor(s, 2, 64);
    s += __shfl_xor(s, 4, 64);
    s += __shfl_xor(s, 8, 64);
    s += __shfl_xor(s, 16, 64);
    s += __shfl_xor(s, 32, 64);
    if (lane == 0) b2[e] = s;
}

// ---------------- Wc = Wg2 @ Wr  (bf16 GEMM, M=N=K=1024, proven 128^2 tile) ----------------
// Wc[e][d] = sum_f Wg[e][H+f] * WrT[d][f]
__global__ __launch_bounds__(256) void k_wc(
    const unsigned short* __restrict__ Wgb,   // [H][2H] bf16
    const unsigned short* __restrict__ WrT,   // [H][H] bf16 (k-major)
    unsigned short* __restrict__ Wc)          // [H][H] bf16
{
    __shared__ unsigned short As[TM * BK];
    __shared__ unsigned short Bs[TM * BK];

    const int tid = threadIdx.x;
    const int bm = blockIdx.x >> 3;
    const int bn = blockIdx.x & 7;
    const int m0 = bm * TM, n0 = bn * TM;

    const int wid = tid >> 6, lane = tid & 63;
    const int wm = (wid >> 1) * 64, wn = (wid & 1) * 64;
    const int lr = lane & 15, kq = lane >> 4;
    const int lane8 = lane >> 3;
    const int c8s = ((lane & 7) ^ lane8) * 8;
    const int sw = lr & 7;

    f32x4 acc[4][4];
#pragma unroll
    for (int i = 0; i < 4; i++)
#pragma unroll
        for (int j = 0; j < 4; j++) acc[i][j] = (f32x4)0.0f;

    for (int kt = 0; kt < H / BK; ++kt) {
        const int k0 = kt * BK;
#pragma unroll
        for (int it = 0; it < 4; ++it) {
            const int sb = it * 4 + wid;
            const int row = sb * 8 + lane8;
            gload16(Wgb + (size_t)(m0 + row) * H2 + H + k0 + c8s, &As[sb * 512]);
            gload16(WrT + (size_t)(n0 + row) * H + k0 + c8s, &Bs[sb * 512]);
        }
        __syncthreads();
#pragma unroll
        for (int ks = 0; ks < BK; ks += 32) {
            const int off = ((((ks >> 3) + kq) ^ sw) << 3);
            short8 a[4], b[4];
#pragma unroll
            for (int i = 0; i < 4; i++)
                a[i] = *reinterpret_cast<const short8*>(&As[(wm + i*16 + lr) * BK + off]);
#pragma unroll
            for (int j = 0; j < 4; j++)
                b[j] = *reinterpret_cast<const short8*>(&Bs[(wn + j*16 + lr) * BK + off]);
#pragma unroll
            for (int i = 0; i < 4; i++)
#pragma unroll
                for (int j = 0; j < 4; j++)
                    acc[i][j] = __builtin_amdgcn_mfma_f32_16x16x32_bf16(a[i], b[j], acc[i][j], 0, 0, 0);
        }
        __syncthreads();
    }

#pragma unroll
    for (int i = 0; i < 4; i++) {
        int gmBase = m0 + wm + i*16 + kq*4;
#pragma unroll
        for (int j2 = 0; j2 < 4; j2++) {
            int gn = n0 + wn + j2*16 + lr;
#pragma unroll
            for (int e = 0; e < 4; e++)
                Wc[(size_t)(gmBase + e) * H + gn] = f2bf(acc[i][j2][e]);
        }
    }
}

// ---------------- fused: 3 GEMMs sharing A-tile + mix + gate + blend ----------------
// per block: out tile [128m x 64n]; per K-tile stage A once + 3 B panels.
__global__ __launch_bounds__(256) void k_fused(
    const unsigned short* __restrict__ xb,    // [MTOK][H] bf16
    const unsigned short* __restrict__ Wrb,   // [H][H] bf16
    const unsigned short* __restrict__ Wcb,   // [H][H] bf16
    const unsigned short* __restrict__ Wgb,   // [H][2H] bf16 (first-half cols = Wg1)
    const float* __restrict__ br,
    const float* __restrict__ b2,             // br @ Wg2^T
    const float* __restrict__ bg,
    const float* __restrict__ wsR, const float* __restrict__ wsBS,
    float* __restrict__ out)
{
    __shared__ unsigned short As[TM * BK];    // 16 KB
    __shared__ unsigned short Bp[TN * BK];    // 8 KB
    __shared__ unsigned short Bc[TN * BK];    // 8 KB
    __shared__ unsigned short Bg1[TN * BK];   // 8 KB
    __shared__ float Rs[64];
    __shared__ float BSs[8];

    const int tid = threadIdx.x;
    // XCD-chunked bijective swizzle: nwg = 8192, 1024 per XCD
    const int l = (blockIdx.x & 7) * 1024 + (blockIdx.x >> 3);
    const int bm = l >> 4;                    // 512 m-blocks
    const int bn = l & 15;                    // 16 n-blocks
    const int m0 = bm * TM, n0 = bn * TN;

    if (tid < 64) Rs[tid] = wsR[tid];
    if (tid < 8)  BSs[tid] = wsBS[tid];

    const int wid = tid >> 6, lane = tid & 63;
    const int wm = (wid >> 1) * 64;           // 2 m-waves
    const int wn = (wid & 1) * 32;            // 2 n-waves
    const int lr = lane & 15, kq = lane >> 4;
    const int lane8 = lane >> 3;
    const int c8s = ((lane & 7) ^ lane8) * 8; // pre-swizzled 16B slot
    const int sw = lr & 7;

    f32x4 accP[4][2], accC[4][2], accG[4][2];
#pragma unroll
    for (int i = 0; i < 4; i++)
#pragma unroll
        for (int j = 0; j < 2; j++) {
            accP[i][j] = (f32x4)0.0f; accC[i][j] = (f32x4)0.0f; accG[i][j] = (f32x4)0.0f;
        }

    for (int kt = 0; kt < H / BK; ++kt) {
        const int k0 = kt * BK;
#pragma unroll
        for (int r = 0; r < 4; ++r) {         // A: 128 rows
            const int sb = r * 4 + wid;
            const int row = sb * 8 + lane8;
            gload16(xb + (size_t)(m0 + row) * H + k0 + c8s, &As[sb * 512]);
        }
#pragma unroll
        for (int r = 0; r < 2; ++r) {         // B panels: 64 rows each
            const int sb = r * 4 + wid;
            const int row = sb * 8 + lane8;
            gload16(Wrb + (size_t)(n0 + row) * H + k0 + c8s, &Bp[sb * 512]);
            gload16(Wcb + (size_t)(n0 + row) * H + k0 + c8s, &Bc[sb * 512]);
            gload16(Wgb + (size_t)(n0 + row) * H2 + k0 + c8s, &Bg1[sb * 512]);
        }
        __syncthreads();
#pragma unroll
        for (int ks = 0; ks < BK; ks += 32) {
            const int off = ((((ks >> 3) + kq) ^ sw) << 3);
            short8 a[4], pb[2], cb[2], gb[2];
#pragma unroll
            for (int i = 0; i < 4; i++)
                a[i] = *reinterpret_cast<const short8*>(&As[(wm + i*16 + lr) * BK + off]);
#pragma unroll
            for (int j = 0; j < 2; j++) {
                pb[j] = *reinterpret_cast<const short8*>(&Bp[(wn + j*16 + lr) * BK + off]);
                cb[j] = *reinterpret_cast<const short8*>(&Bc[(wn + j*16 + lr) * BK + off]);
                gb[j] = *reinterpret_cast<const short8*>(&Bg1[(wn + j*16 + lr) * BK + off]);
            }
#pragma unroll
            for (int i = 0; i < 4; i++)
#pragma unroll
                for (int j = 0; j < 2; j++) {
                    accP[i][j] = __builtin_amdgcn_mfma_f32_16x16x32_bf16(a[i], pb[j], accP[i][j], 0, 0, 0);
                    accC[i][j] = __builtin_amdgcn_mfma_f32_16x16x32_bf16(a[i], cb[j], accC[i][j], 0, 0, 0);
                    accG[i][j] = __builtin_amdgcn_mfma_f32_16x16x32_bf16(a[i], gb[j], accG[i][j], 0, 0, 0);
                }
        }
        __syncthreads();
    }

    // epilogue: limb-mix P and C accs, gate, blend, store fp32
    const int lowbit = kq & 1;
    float rc[4][8];
#pragma unroll
    for (int e = 0; e < 4; e++)
#pragma unroll
        for (int jj = 0; jj < 8; jj++) rc[e][jj] = Rs[(lowbit*4 + e)*8 + jj];
    float bsc[4];
#pragma unroll
    for (int e = 0; e < 4; e++) bsc[e] = BSs[lowbit*4 + e];

#pragma unroll
    for (int i = 0; i < 4; i++) {
        const int gmBase = m0 + wm + i*16 + kq*4;
#pragma unroll
        for (int j2 = 0; j2 < 2; j2++) {
            const int gn = n0 + wn + j2*16 + lr;
            const float brv = br[gn];
            const float b2v = b2[gn];
            const float bgv = bg[gn];
            float ownP[4], othP[4], ownC[4], othC[4];
#pragma unroll
            for (int e = 0; e < 4; e++) {
                ownP[e] = accP[i][j2][e];  othP[e] = __shfl_xor(ownP[e], 16, 64);
                ownC[e] = accC[i][j2][e];  othC[e] = __shfl_xor(ownC[e], 16, 64);
            }
            float g8P[8], g8C[8];
#pragma unroll
            for (int e = 0; e < 4; e++) {
                if (lowbit == 0) { g8P[e] = ownP[e]; g8P[4+e] = othP[e];
                                   g8C[e] = ownC[e]; g8C[4+e] = othC[e]; }
                else             { g8P[e] = othP[e]; g8P[4+e] = ownP[e];
                                   g8C[e] = othC[e]; g8C[4+e] = ownC[e]; }
            }
#pragma unroll
            for (int e = 0; e < 4; e++) {
                float mp = 0.0f, mc = 0.0f;
#pragma unroll
                for (int jj = 0; jj < 8; jj++) {
                    mp += rc[e][jj] * g8P[jj];
                    mc += rc[e][jj] * g8C[jj];
                }
                mp += bsc[e] * brv;           // routed[m][gn]
                mc += bsc[e] * b2v;           // (routed @ Wg2^T)[m][gn] contribution
                const float t = accG[i][j2][e] + mc + bgv;
                const float g = 1.0f / (1.0f + expf(-t));
                const size_t idx = (size_t)(gmBase + e) * H + gn;
                const float xv = bf2f(xb[idx]);
                out[idx] = g * mp + (1.0f - g) * xv;
            }
        }
    }
}

// ---------------- fallback (small ws): fully fused, fp32 vector ----------------
__global__ __launch_bounds__(256) void k_fallback(
    const float* __restrict__ x, const float* __restrict__ Wr, const float* __restrict__ br,
    const float* __restrict__ Wg, const float* __restrict__ bg,
    const float* __restrict__ wsR, const float* __restrict__ wsBS,
    float* __restrict__ out)
{
    __shared__ float xs[8][H];
    __shared__ float rt[8][H];
    __shared__ float Rs[64];
    __shared__ float BSs[8];

    const int tid = threadIdx.x;
    const size_t base = (size_t)blockIdx.x * (8 * H);
    if (tid < 64) Rs[tid] = wsR[tid];
    if (tid < 8)  BSs[tid] = wsBS[tid];

#pragma unroll
    for (int it = 0; it < 8; ++it) {
        int s = it * 256 + tid;
        reinterpret_cast<float4*>(&xs[0][0])[s] = reinterpret_cast<const float4*>(x + base)[s];
    }
    __syncthreads();

    for (int eo = 0; eo < 4; ++eo) {
        int e = eo * 256 + tid;
        float acc[8];
#pragma unroll
        for (int l = 0; l < 8; l++) acc[l] = 0.0f;
        const float* w = Wr + (size_t)e * H;
        for (int k = 0; k < H; k += 4) {
            float4 wv = *reinterpret_cast<const float4*>(w + k);
#pragma unroll
            for (int l = 0; l < 8; l++)
                acc[l] += wv.x * xs[l][k] + wv.y * xs[l][k+1] + wv.z * xs[l][k+2] + wv.w * xs[l][k+3];
        }
        float brv = br[e];
#pragma unroll
        for (int l = 0; l < 8; l++) {
            float m = 0.0f;
#pragma unroll
            for (int j = 0; j < 8; j++) m += Rs[l*8 + j] * acc[j];
            rt[l][e] = m + BSs[l] * brv;
        }
    }
    __syncthreads();

    for (int eo = 0; eo < 4; ++eo) {
        int e = eo * 256 + tid;
        float acc2[8];
#pragma unroll
        for (int l = 0; l < 8; l++) acc2[l] = 0.0f;
        const float* w1 = Wg + (size_t)e * (2 * H);
        for (int k = 0; k < H; k += 4) {
            float4 wv = *reinterpret_cast<const float4*>(w1 + k);
#pragma unroll
            for (int l = 0; l < 8; l++)
                acc2[l] += wv.x * xs[l][k] + wv.y * xs[l][k+1] + wv.z * xs[l][k+2] + wv.w * xs[l][k+3];
        }
        const float* w2 = w1 + H;
        for (int k = 0; k < H; k += 4) {
            float4 wv = *reinterpret_cast<const float4*>(w2 + k);
#pragma unroll
            for (int l = 0; l < 8; l++)
                acc2[l] += wv.x * rt[l][k] + wv.y * rt[l][k+1] + wv.z * rt[l][k+2] + wv.w * rt[l][k+3];
        }
        float bgv = bg[e];
#pragma unroll
        for (int l = 0; l < 8; l++) {
            float t = acc2[l] + bgv;
            float g = 1.0f / (1.0f + expf(-t));
            out[base + (size_t)l * H + e] = g * rt[l][e] + (1.0f - g) * xs[l][e];
        }
    }
}

extern "C" void kernel_launch(void* const* d_in, const int* in_sizes, int n_in,
                              void* d_out, int out_size, void* d_ws, size_t ws_size,
                              hipStream_t stream) {
    const float* x   = (const float*)d_in[0];
    const float* lp  = (const float*)d_in[1];
    const float* thr = (const float*)d_in[2];
    const float* Wr  = (const float*)d_in[3];
    const float* br  = (const float*)d_in[4];
    const float* Wg  = (const float*)d_in[5];
    const float* bg  = (const float*)d_in[6];
    float* out = (float*)d_out;
    char* ws = (char*)d_ws;

    float* wsR  = (float*)(ws + WS_R_OFF);
    float* wsBS = (float*)(ws + WS_BS_OFF);

    k_routing<<<1, 64, 0, stream>>>(lp, thr, wsR, wsBS);

    if (ws_size >= WS_NEED) {
        unsigned short* wsWr  = (unsigned short*)(ws + WS_WR_OFF);
        unsigned short* wsWg  = (unsigned short*)(ws + WS_WG_OFF);
        unsigned short* wsWrT = (unsigned short*)(ws + WS_WRT_OFF);
        unsigned short* wsWc  = (unsigned short*)(ws + WS_WC_OFF);
        unsigned short* wsXb  = (unsigned short*)(ws + WS_XB_OFF);
        float* wsB2 = (float*)(ws + WS_B2_OFF);

        k_f32_to_bf16<<<512, 256, 0, stream>>>(Wr, wsWr, (1024 * 1024) / 4);
        k_f32_to_bf16<<<1024, 256, 0, stream>>>(Wg, wsWg, (1024 * 2048) / 4);
        k_transp<<<256, 256, 0, stream>>>(Wr, wsWrT);
        k_brw2<<<1024, 64, 0, stream>>>(br, Wg, wsB2);
        k_wc<<<64, 256, 0, stream>>>(wsWg, wsWrT, wsWc);
        k_f32_to_bf16<<<4096, 256, 0, stream>>>(x, wsXb, (MTOK * H) / 4);
        k_fused<<<(MTOK / TM) * (H / TN), 256, 0, stream>>>(
            wsXb, wsWr, wsWc, wsWg, br, wsB2, bg, wsR, wsBS, out);
    } else {
        k_fallback<<<MTOK / 8, 256, 0, stream>>>(x, Wr, br, Wg, bg, wsR, wsBS, out);
    }
}

// Round 6
// 797.957 us; speedup vs baseline: 1.4506x; 1.4506x over previous
//
#include <hip/hip_runtime.h>
#include <math.h>

#define H 1024
#define H2 2048
#define MTOK 65536          // B*S*L = 4*2048*8
#define TM 128
#define BK 64
#define NT1 (H / BK)        // 16 K-tiles pass1
#define NT2 (H2 / BK)       // 32 K-tiles pass2

typedef __attribute__((ext_vector_type(8))) short short8;
typedef __attribute__((ext_vector_type(4))) float f32x4;

// ---------------- ws layout (bytes) ----------------
#define WS_R_OFF   0                          // 64 floats
#define WS_BS_OFF  256                        // 8 floats
#define WS_WR_OFF  4096                       // bf16 1024*1024   (2 MB)
#define WS_WG_OFF  (4096 + 2*1024*1024)       // bf16 1024*2048   (4 MB)
#define WS_RT_OFF  (8ull*1024*1024)           // bf16 MTOK*1024   (128 MB)
#define WS_XB_OFF  (WS_RT_OFF + (size_t)MTOK*H*2)   // bf16 MTOK*1024 (128 MB)
#define WS_NEED_FULL (WS_XB_OFF + (size_t)MTOK*H*2)

static __device__ __forceinline__ unsigned short f2bf(float f) {
    unsigned int u = __float_as_uint(f);
    u = u + 0x7fffu + ((u >> 16) & 1u);       // RNE
    return (unsigned short)(u >> 16);
}
static __device__ __forceinline__ float bf2f(unsigned short s) {
    return __uint_as_float(((unsigned int)s) << 16);
}
static __device__ __forceinline__ void gload16(const void* g, void* l) {
    __builtin_amdgcn_global_load_lds(
        (const __attribute__((address_space(1))) void*)g,
        (__attribute__((address_space(3))) void*)l, 16, 0, 0);
}

// ---------------- routing matrix ----------------
__global__ void k_routing(const float* __restrict__ lp, const float* __restrict__ thr,
                          float* __restrict__ wsR, float* __restrict__ wsBS) {
    int t = threadIdx.x;            // 0..63
    int i = t >> 3, j = t & 7;
    float mx = 0.5f * (lp[i*3+0] + lp[j*3+0]);
    float my = 0.5f * (lp[i*3+1] + lp[j*3+1]);
    float mz = 0.5f * (lp[i*3+2] + lp[j*3+2]);
    float f = sinf(mx)*cosf(my) + sinf(my)*cosf(mz) + sinf(mz)*cosf(mx) - thr[0];
    float r = 1.0f / (1.0f + expf(-2.0f * f));
    if (i == j) r = 1.0f;
    float s = r;
    s += __shfl_xor(s, 1, 64);
    s += __shfl_xor(s, 2, 64);
    s += __shfl_xor(s, 4, 64);
    float R = r / (s + 1e-6f);
    wsR[t] = R;
    if (j == 0) wsBS[i] = s / (s + 1e-6f);
}

// ---------------- fp32 -> bf16 convert ----------------
__global__ void k_f32_to_bf16(const float* __restrict__ src, unsigned short* __restrict__ dst, int n4) {
    int i = blockIdx.x * blockDim.x + threadIdx.x;
    int stride = gridDim.x * blockDim.x;
    for (; i < n4; i += stride) {
        float4 v = reinterpret_cast<const float4*>(src)[i];
        ushort4 o = make_ushort4(f2bf(v.x), f2bf(v.y), f2bf(v.z), f2bf(v.w));
        reinterpret_cast<ushort4*>(dst)[i] = o;
    }
}

// =====================================================================
// FAST TIER: all-bf16 GEMMs, m97 structure + T2 both-sides XOR swizzle
// + 2-stage double-buffered prefetch (one __syncthreads per K-tile:
//   its implicit vmcnt(0) drains NEXT tile's loads, issued before compute,
//   and the barrier protects the buffer about to be overwritten).
// =====================================================================

// pass 1: routed = mix(xb @ Wr^T) + scale*b
__global__ __launch_bounds__(256) void k_p1b(
    const unsigned short* __restrict__ xb,   // [MTOK][H] bf16
    const unsigned short* __restrict__ Wr,   // [H][H] bf16
    const float* __restrict__ b_route,
    const float* __restrict__ wsR, const float* __restrict__ wsBS,
    unsigned short* __restrict__ routed)
{
    __shared__ unsigned short As[2][TM * BK];   // 2 x 16 KB
    __shared__ unsigned short Bs[2][TM * BK];   // 2 x 16 KB
    __shared__ float Rs[64];
    __shared__ float BSs[8];

    const int tid = threadIdx.x;
    // XCD-chunked bijective swizzle: nwg=4096, 512 per XCD
    const int l = (blockIdx.x & 7) * 512 + (blockIdx.x >> 3);
    const int bm = l >> 3;
    const int bn = l & 7;
    const int m0 = bm * TM;
    const int n0 = bn * TM;

    if (tid < 64) Rs[tid] = wsR[tid];
    if (tid < 8)  BSs[tid] = wsBS[tid];

    const int wid  = tid >> 6;
    const int lane = tid & 63;
    const int wm = (wid >> 1) * 64;
    const int wn = (wid & 1) * 64;
    const int lr = lane & 15;
    const int kq = lane >> 4;

    const int lane8 = lane >> 3;                  // row within 8-row group
    const int c8s   = ((lane & 7) ^ lane8) * 8;   // pre-swizzled 16B slot (elems)
    const int sw = lr & 7;                        // read-side swizzle key

    f32x4 acc[4][4];
#pragma unroll
    for (int i = 0; i < 4; i++)
#pragma unroll
        for (int j = 0; j < 4; j++) acc[i][j] = (f32x4)0.0f;

    // per-thread staging bases (hoisted; advance by BK per tile)
    const unsigned short* ga[4];
    const unsigned short* gb[4];
#pragma unroll
    for (int it = 0; it < 4; ++it) {
        const int sb = it * 4 + wid;
        const int row = sb * 8 + lane8;
        ga[it] = xb + (size_t)(m0 + row) * H + c8s;
        gb[it] = Wr + (size_t)(n0 + row) * H + c8s;
    }

#define P1_STAGE(buf, kt)                                             \
    {                                                                 \
        const int _k0 = (kt) * BK;                                    \
        _Pragma("unroll")                                             \
        for (int it = 0; it < 4; ++it) {                              \
            const int sb = it * 4 + wid;                              \
            gload16(ga[it] + _k0, &As[buf][sb * 512]);                \
            gload16(gb[it] + _k0, &Bs[buf][sb * 512]);                \
        }                                                             \
    }

    P1_STAGE(0, 0);
    __syncthreads();                 // drains buf0 loads

    for (int kt = 0; kt < NT1; ++kt) {
        const int cur = kt & 1;
        if (kt + 1 < NT1) P1_STAGE(cur ^ 1, kt + 1);
#pragma unroll
        for (int ks = 0; ks < BK; ks += 32) {
            const int off = ((((ks >> 3) + kq) ^ sw) << 3);
            short8 a[4], b[4];
#pragma unroll
            for (int i = 0; i < 4; i++)
                a[i] = *reinterpret_cast<const short8*>(&As[cur][(wm + i*16 + lr) * BK + off]);
#pragma unroll
            for (int j = 0; j < 4; j++)
                b[j] = *reinterpret_cast<const short8*>(&Bs[cur][(wn + j*16 + lr) * BK + off]);
#pragma unroll
            for (int i = 0; i < 4; i++)
#pragma unroll
                for (int j = 0; j < 4; j++)
                    acc[i][j] = __builtin_amdgcn_mfma_f32_16x16x32_bf16(a[i], b[j], acc[i][j], 0, 0, 0);
        }
        __syncthreads();             // drains next-tile loads + protects buffer swap
    }

    // epilogue: limb mix (rows grouped by 8) + bias, store bf16
    const int lowbit = kq & 1;
    float rc[4][8];
#pragma unroll
    for (int e = 0; e < 4; e++)
#pragma unroll
        for (int jj = 0; jj < 8; jj++) rc[e][jj] = Rs[(lowbit*4 + e)*8 + jj];
    float bsc[4];
#pragma unroll
    for (int e = 0; e < 4; e++) bsc[e] = BSs[lowbit*4 + e];

#pragma unroll
    for (int i = 0; i < 4; i++) {
        int gmBase = m0 + wm + i*16 + kq*4;
#pragma unroll
        for (int j2 = 0; j2 < 4; j2++) {
            int gn = n0 + wn + j2*16 + lr;
            float br = b_route[gn];
            float own[4], oth[4];
#pragma unroll
            for (int e = 0; e < 4; e++) {
                own[e] = acc[i][j2][e];
                oth[e] = __shfl_xor(own[e], 16, 64);
            }
            float g8[8];
#pragma unroll
            for (int e = 0; e < 4; e++) {
                if (lowbit == 0) { g8[e] = own[e]; g8[4+e] = oth[e]; }
                else             { g8[e] = oth[e]; g8[4+e] = own[e]; }
            }
#pragma unroll
            for (int e = 0; e < 4; e++) {
                float m = 0.0f;
#pragma unroll
                for (int jj = 0; jj < 8; jj++) m += rc[e][jj] * g8[jj];
                m += bsc[e] * br;
                routed[(size_t)(gmBase + e) * H + gn] = f2bf(m);
            }
        }
    }
}

// pass 2: out = g*routed + (1-g)*x,  g = sigmoid([xb|routed] @ Wg^T + b)
__global__ __launch_bounds__(256) void k_p2b(
    const unsigned short* __restrict__ xb,     // [MTOK][H] bf16
    const unsigned short* __restrict__ Wg,     // [H][2H] bf16
    const float* __restrict__ b_gate,
    const unsigned short* __restrict__ routed, // [MTOK][H] bf16
    float* __restrict__ out)
{
    __shared__ unsigned short As[2][TM * BK];
    __shared__ unsigned short Bs[2][TM * BK];

    const int tid = threadIdx.x;
    const int l = (blockIdx.x & 7) * 512 + (blockIdx.x >> 3);
    const int bm = l >> 3;
    const int bn = l & 7;
    const int m0 = bm * TM;
    const int n0 = bn * TM;

    const int wid  = tid >> 6;
    const int lane = tid & 63;
    const int wm = (wid >> 1) * 64;
    const int wn = (wid & 1) * 64;
    const int lr = lane & 15;
    const int kq = lane >> 4;

    const int lane8 = lane >> 3;
    const int c8s   = ((lane & 7) ^ lane8) * 8;
    const int sw = lr & 7;

    f32x4 acc[4][4];
#pragma unroll
    for (int i = 0; i < 4; i++)
#pragma unroll
        for (int j = 0; j < 4; j++) acc[i][j] = (f32x4)0.0f;

    // staging bases: A has two sources (xb for k<H, routed for k>=H, same row stride)
    const unsigned short* gax[4];   // xb base
    const unsigned short* gar[4];   // routed base
    const unsigned short* gb[4];
#pragma unroll
    for (int it = 0; it < 4; ++it) {
        const int sb = it * 4 + wid;
        const int row = sb * 8 + lane8;
        gax[it] = xb     + (size_t)(m0 + row) * H + c8s;
        gar[it] = routed + (size_t)(m0 + row) * H + c8s;
        gb[it]  = Wg     + (size_t)(n0 + row) * H2 + c8s;
    }

#define P2_STAGE(buf, kt)                                                   \
    {                                                                       \
        const int _k0 = (kt) * BK;                                          \
        const bool _fx = (kt) < NT1;                                        \
        const int _ka = _fx ? _k0 : (_k0 - H);                              \
        _Pragma("unroll")                                                   \
        for (int it = 0; it < 4; ++it) {                                    \
            const int sb = it * 4 + wid;                                    \
            gload16((_fx ? gax[it] : gar[it]) + _ka, &As[buf][sb * 512]);   \
            gload16(gb[it] + _k0, &Bs[buf][sb * 512]);                      \
        }                                                                   \
    }

    P2_STAGE(0, 0);
    __syncthreads();

    for (int kt = 0; kt < NT2; ++kt) {
        const int cur = kt & 1;
        if (kt + 1 < NT2) P2_STAGE(cur ^ 1, kt + 1);
#pragma unroll
        for (int ks = 0; ks < BK; ks += 32) {
            const int off = ((((ks >> 3) + kq) ^ sw) << 3);
            short8 a[4], b[4];
#pragma unroll
            for (int i = 0; i < 4; i++)
                a[i] = *reinterpret_cast<const short8*>(&As[cur][(wm + i*16 + lr) * BK + off]);
#pragma unroll
            for (int j = 0; j < 4; j++)
                b[j] = *reinterpret_cast<const short8*>(&Bs[cur][(wn + j*16 + lr) * BK + off]);
#pragma unroll
            for (int i = 0; i < 4; i++)
#pragma unroll
                for (int j = 0; j < 4; j++)
                    acc[i][j] = __builtin_amdgcn_mfma_f32_16x16x32_bf16(a[i], b[j], acc[i][j], 0, 0, 0);
        }
        __syncthreads();
    }

    // epilogue: sigmoid gate + blend (reads are L1/L2-warm: same rows just staged)
#pragma unroll
    for (int i = 0; i < 4; i++) {
        int gmBase = m0 + wm + i*16 + kq*4;
#pragma unroll
        for (int j2 = 0; j2 < 4; j2++) {
            int gn = n0 + wn + j2*16 + lr;
            float bg = b_gate[gn];
#pragma unroll
            for (int e = 0; e < 4; e++) {
                size_t idx = (size_t)(gmBase + e) * H + gn;
                float t = acc[i][j2][e] + bg;
                float g = 1.0f / (1.0f + expf(-t));
                float rt = bf2f(routed[idx]);
                float xv = bf2f(xb[idx]);
                out[idx] = g * rt + (1.0f - g) * xv;
            }
        }
    }
}

// ---------------- fallback (small ws): fully fused, fp32 vector ----------------
__global__ __launch_bounds__(256) void k_fallback(
    const float* __restrict__ x, const float* __restrict__ Wr, const float* __restrict__ br,
    const float* __restrict__ Wg, const float* __restrict__ bg,
    const float* __restrict__ wsR, const float* __restrict__ wsBS,
    float* __restrict__ out)
{
    __shared__ float xs[8][H];
    __shared__ float rt[8][H];
    __shared__ float Rs[64];
    __shared__ float BSs[8];

    const int tid = threadIdx.x;
    const size_t base = (size_t)blockIdx.x * (8 * H);
    if (tid < 64) Rs[tid] = wsR[tid];
    if (tid < 8)  BSs[tid] = wsBS[tid];

#pragma unroll
    for (int it = 0; it < 8; ++it) {
        int s = it * 256 + tid;
        reinterpret_cast<float4*>(&xs[0][0])[s] = reinterpret_cast<const float4*>(x + base)[s];
    }
    __syncthreads();

    for (int eo = 0; eo < 4; ++eo) {
        int e = eo * 256 + tid;
        float acc[8];
#pragma unroll
        for (int l = 0; l < 8; l++) acc[l] = 0.0f;
        const float* w = Wr + (size_t)e * H;
        for (int k = 0; k < H; k += 4) {
            float4 wv = *reinterpret_cast<const float4*>(w + k);
#pragma unroll
            for (int l = 0; l < 8; l++)
                acc[l] += wv.x * xs[l][k] + wv.y * xs[l][k+1] + wv.z * xs[l][k+2] + wv.w * xs[l][k+3];
        }
        float brv = br[e];
#pragma unroll
        for (int l = 0; l < 8; l++) {
            float m = 0.0f;
#pragma unroll
            for (int j = 0; j < 8; j++) m += Rs[l*8 + j] * acc[j];
            rt[l][e] = m + BSs[l] * brv;
        }
    }
    __syncthreads();

    for (int eo = 0; eo < 4; ++eo) {
        int e = eo * 256 + tid;
        float acc2[8];
#pragma unroll
        for (int l = 0; l < 8; l++) acc2[l] = 0.0f;
        const float* w1 = Wg + (size_t)e * (2 * H);
        for (int k = 0; k < H; k += 4) {
            float4 wv = *reinterpret_cast<const float4*>(w1 + k);
#pragma unroll
            for (int l = 0; l < 8; l++)
                acc2[l] += wv.x * xs[l][k] + wv.y * xs[l][k+1] + wv.z * xs[l][k+2] + wv.w * xs[l][k+3];
        }
        const float* w2 = w1 + H;
        for (int k = 0; k < H; k += 4) {
            float4 wv = *reinterpret_cast<const float4*>(w2 + k);
#pragma unroll
            for (int l = 0; l < 8; l++)
                acc2[l] += wv.x * rt[l][k] + wv.y * rt[l][k+1] + wv.z * rt[l][k+2] + wv.w * rt[l][k+3];
        }
        float bgv = bg[e];
#pragma unroll
        for (int l = 0; l < 8; l++) {
            float t = acc2[l] + bgv;
            float g = 1.0f / (1.0f + expf(-t));
            out[base + (size_t)l * H + e] = g * rt[l][e] + (1.0f - g) * xs[l][e];
        }
    }
}

extern "C" void kernel_launch(void* const* d_in, const int* in_sizes, int n_in,
                              void* d_out, int out_size, void* d_ws, size_t ws_size,
                              hipStream_t stream) {
    const float* x   = (const float*)d_in[0];
    const float* lp  = (const float*)d_in[1];
    const float* thr = (const float*)d_in[2];
    const float* Wr  = (const float*)d_in[3];
    const float* br  = (const float*)d_in[4];
    const float* Wg  = (const float*)d_in[5];
    const float* bg  = (const float*)d_in[6];
    float* out = (float*)d_out;
    char* ws = (char*)d_ws;

    float* wsR  = (float*)(ws + WS_R_OFF);
    float* wsBS = (float*)(ws + WS_BS_OFF);

    k_routing<<<1, 64, 0, stream>>>(lp, thr, wsR, wsBS);

    if (ws_size >= WS_NEED_FULL) {
        unsigned short* wsWr = (unsigned short*)(ws + WS_WR_OFF);
        unsigned short* wsWg = (unsigned short*)(ws + WS_WG_OFF);
        unsigned short* wsRt = (unsigned short*)(ws + WS_RT_OFF);
        unsigned short* wsXb = (unsigned short*)(ws + WS_XB_OFF);
        k_f32_to_bf16<<<512, 256, 0, stream>>>(Wr, wsWr, (1024 * 1024) / 4);
        k_f32_to_bf16<<<1024, 256, 0, stream>>>(Wg, wsWg, (1024 * 2048) / 4);
        k_f32_to_bf16<<<4096, 256, 0, stream>>>(x, wsXb, (MTOK * H) / 4);
        k_p1b<<<(MTOK / TM) * (H / TM), 256, 0, stream>>>(wsXb, wsWr, br, wsR, wsBS, wsRt);
        k_p2b<<<(MTOK / TM) * (H / TM), 256, 0, stream>>>(wsXb, wsWg, bg, wsRt, out);
    } else {
        k_fallback<<<MTOK / 8, 256, 0, stream>>>(x, Wr, br, Wg, bg, wsR, wsBS, out);
    }
}